// Round 12
// baseline (326.283 us; speedup 1.0000x reference)
//
#include <hip/hip_runtime.h>
#include <hip/hip_fp16.h>

static inline int cdiv(long long a, long long b) { return (int)((a + b - 1) / b); }

typedef _Float16 half8 __attribute__((ext_vector_type(8)));
typedef float f32x4 __attribute__((ext_vector_type(4)));

#define NBSH 8            // 256 dsts per bucket
#define BCAP 6144         // bucket capacity in ebuf (avg 4096 for this graph; +50%)
#define BCHUNK 8192       // edges per k_bin block

// ---------------- binned CSR build (no global per-dst atomics) ----------------
__global__ void k_zero_bin(int* bcnt, int* ovf_cnt, int nbk) {
    int t = blockIdx.x * blockDim.x + threadIdx.x;
    if (t < nbk) bcnt[t] = 0;
    if (t == 0) *ovf_cnt = 0;
}

__global__ __launch_bounds__(256) void k_bin(const int* __restrict__ ei, int E, int nbk,
                                             int* __restrict__ bcnt,
                                             int2* __restrict__ ebuf,
                                             int2* __restrict__ ovf, int* __restrict__ ovf_cnt) {
    __shared__ int hist[1024];
    __shared__ int base[1024];
    const int tid = threadIdx.x;
    const int e0 = blockIdx.x * BCHUNK;
    if (e0 >= E) return;
    const int n = min(BCHUNK, E - e0);
    const int* __restrict__ srcs = ei + e0;
    const int* __restrict__ dsts = ei + E + e0;

    for (int i = tid; i < nbk; i += 256) hist[i] = 0;
    __syncthreads();
    for (int i = tid; i < n; i += 256) atomicAdd(&hist[dsts[i] >> NBSH], 1);
    __syncthreads();
    for (int b = tid; b < nbk; b += 256) {
        int h = hist[b];
        base[b] = h ? atomicAdd(&bcnt[b], h) : 0;
        hist[b] = 0;  // reuse as local offset
    }
    __syncthreads();
    for (int i = tid; i < n; i += 256) {
        int d = dsts[i];
        int s = srcs[i];
        int b = d >> NBSH;
        int pos = base[b] + atomicAdd(&hist[b], 1);
        if (pos < BCAP) {
            ebuf[(size_t)b * BCAP + pos] = make_int2(s, d);
        } else {
            int op = atomicAdd(ovf_cnt, 1);
            ovf[op] = make_int2(s, d);
        }
    }
}

__global__ __launch_bounds__(1024) void k_bscan(const int* __restrict__ bcnt,
                                                int* __restrict__ bbase,
                                                int* __restrict__ row_ptr, int nbk, int N) {
    __shared__ int s[1024];
    const int t = threadIdx.x;
    int v = (t < nbk) ? bcnt[t] : 0;
    s[t] = v;
    __syncthreads();
    for (int off = 1; off < 1024; off <<= 1) {
        int u = (t >= off) ? s[t - off] : 0;
        __syncthreads();
        s[t] += u;
        __syncthreads();
    }
    if (t < nbk) bbase[t] = s[t] - v;
    if (t == nbk - 1) row_ptr[N] = s[t];
}

__global__ __launch_bounds__(256) void k_passB1(const int* __restrict__ bcnt,
                                                const int* __restrict__ bbase,
                                                const int2* __restrict__ ebuf,
                                                const int2* __restrict__ ovf,
                                                const int* __restrict__ ovf_cnt,
                                                int* __restrict__ row_ptr,
                                                float* __restrict__ dis, int N) {
    __shared__ int ldeg[256];
    __shared__ int sc[256];
    const int tid = threadIdx.x;
    const int b = blockIdx.x;
    const int d0 = b << NBSH;
    const int dn = min(1 << NBSH, N - d0);
    ldeg[tid] = 0;
    __syncthreads();
    const int sz = min(bcnt[b], BCAP);
    const int2* __restrict__ reg = ebuf + (size_t)b * BCAP;
    for (int i = tid; i < sz; i += 256) atomicAdd(&ldeg[reg[i].y - d0], 1);
    const int oc = *ovf_cnt;
    for (int i = tid; i < oc; i += 256) {
        int d = ovf[i].y;
        if ((d >> NBSH) == b) atomicAdd(&ldeg[d - d0], 1);
    }
    __syncthreads();
    sc[tid] = ldeg[tid];
    __syncthreads();
    for (int off = 1; off < 256; off <<= 1) {
        int u = (tid >= off) ? sc[tid - off] : 0;
        __syncthreads();
        sc[tid] += u;
        __syncthreads();
    }
    if (tid < dn) {
        row_ptr[d0 + tid] = bbase[b] + sc[tid] - ldeg[tid];
        dis[d0 + tid] = rsqrtf((float)(ldeg[tid] + 1));  // +1 self-loop
    }
}

__global__ __launch_bounds__(256) void k_passB2(const int* __restrict__ bcnt,
                                                const int2* __restrict__ ebuf,
                                                const int2* __restrict__ ovf,
                                                const int* __restrict__ ovf_cnt,
                                                const int* __restrict__ row_ptr,
                                                const float* __restrict__ dis,
                                                int2* __restrict__ csr, int N) {
    __shared__ int lcur[256];
    const int tid = threadIdx.x;
    const int b = blockIdx.x;
    const int d0 = b << NBSH;
    const int dn = min(1 << NBSH, N - d0);
    lcur[tid] = (tid < dn) ? row_ptr[d0 + tid] : 0;
    __syncthreads();
    const int sz = min(bcnt[b], BCAP);
    const int2* __restrict__ reg = ebuf + (size_t)b * BCAP;
    for (int i = tid; i < sz; i += 256) {
        int2 sd = reg[i];
        float w = dis[sd.x] * dis[sd.y];
        int pos = atomicAdd(&lcur[sd.y - d0], 1);
        csr[pos] = make_int2(sd.x, __float_as_int(w));
    }
    const int oc = *ovf_cnt;
    for (int i = tid; i < oc; i += 256) {
        int2 sd = ovf[i];
        if ((sd.y >> NBSH) != b) continue;
        float w = dis[sd.x] * dis[sd.y];
        int pos = atomicAdd(&lcur[sd.y - d0], 1);
        csr[pos] = make_int2(sd.x, __float_as_int(w));
    }
}

// ---------------- fallback CSR build (round-7 path, used only if ws too small) ----------------
__global__ void k_zero_i(int* p, int n) {
    int t = blockIdx.x * blockDim.x + threadIdx.x;
    if (t < n) p[t] = 0;
}

__global__ void k_count(const int* __restrict__ dst, int* __restrict__ deg, int E) {
    int t = blockIdx.x * blockDim.x + threadIdx.x;
    if (t < E) atomicAdd(&deg[dst[t]], 1);
}

__global__ __launch_bounds__(1024) void k_scan1(const int* __restrict__ deg,
                                                int* __restrict__ tmp,
                                                int* __restrict__ bsum, int n) {
    __shared__ int s[1024];
    const int t = threadIdx.x;
    const int i = blockIdx.x * 1024 + t;
    int v = (i < n) ? deg[i] : 0;
    s[t] = v;
    __syncthreads();
    for (int off = 1; off < 1024; off <<= 1) {
        int u = (t >= off) ? s[t - off] : 0;
        __syncthreads();
        s[t] += u;
        __syncthreads();
    }
    if (i < n) tmp[i] = s[t];
    if (t == 1023) bsum[blockIdx.x] = s[1023];
}

__global__ __launch_bounds__(1024) void k_scan2(int* __restrict__ bsum, int nb) {
    __shared__ int s[1024];
    const int t = threadIdx.x;
    s[t] = (t < nb) ? bsum[t] : 0;
    __syncthreads();
    for (int off = 1; off < 1024; off <<= 1) {
        int u = (t >= off) ? s[t - off] : 0;
        __syncthreads();
        s[t] += u;
        __syncthreads();
    }
    if (t < nb) bsum[t] = s[t];
}

__global__ __launch_bounds__(1024) void k_scan3(const int* __restrict__ deg,
                                                const int* __restrict__ tmp,
                                                const int* __restrict__ bsum,
                                                int* __restrict__ row_ptr,
                                                float* __restrict__ dis,
                                                int* __restrict__ cur, int n, int nb) {
    const int i = blockIdx.x * 1024 + threadIdx.x;
    if (i < n) {
        int off = (blockIdx.x == 0) ? 0 : bsum[blockIdx.x - 1];
        int dgi = deg[i];
        int r = tmp[i] - dgi + off;
        row_ptr[i] = r;
        dis[i] = rsqrtf((float)(dgi + 1));
        cur[i] = r;
    } else if (i == n) {
        row_ptr[n] = bsum[nb - 1];
    }
}

__global__ void k_scatter(const int* __restrict__ ei, const float* __restrict__ dis,
                          int* __restrict__ cur, int2* __restrict__ csr, int E) {
    int e = blockIdx.x * blockDim.x + threadIdx.x;
    if (e >= E) return;
    int s = ei[e];
    int d = ei[e + E];
    float w = dis[s] * dis[d];
    int pos = atomicAdd(&cur[d], 1);
    csr[pos] = make_int2(s, __float_as_int(w));
}

// ---------------- fp32 -> fp16 convert ----------------
__global__ __launch_bounds__(256) void k_cvt_h(const float* __restrict__ in,
                                               __half* __restrict__ out, long long n4) {
    long long t = (long long)blockIdx.x * blockDim.x + threadIdx.x;
    if (t >= n4) return;
    float4 v = *(const float4*)(in + t * 4);
    union { float2 f; __half2 h[2]; } u;
    u.h[0] = __floats2half2_rn(v.x, v.y);
    u.h[1] = __floats2half2_rn(v.z, v.w);
    *(float2*)(out + t * 4) = u.f;
}

// ---------------- weight prep: W fp32 [K][CN] -> swizzled fp16 W^T [CN][K] ----------------
template <int K, int CN>
__global__ void k_prep_wt(const float* __restrict__ W, char* __restrict__ wt) {
    constexpr int CH = K / 8;
    int id = blockIdx.x * blockDim.x + threadIdx.x;
    if (id >= CN * CH) return;
    int n = id / CH, c = id % CH;
    half8 h;
#pragma unroll
    for (int j = 0; j < 8; ++j) h[j] = (_Float16)W[(size_t)(c * 8 + j) * CN + n];
    *(half8*)(wt + (size_t)n * (2 * K) + ((c * 16) ^ ((n & 7) << 4))) = h;
}

// ---------------- vectorized fused aggregation (round-10 structure, unroll 8) ----------------
// out[d][:] = (BIAS? b:0) + dis[d]^2*in[d][:] + sum_e w_e*in[src_e][:]; optional ReLU.
// C/8 lanes per row (16B half8 loads), 64/(C/8) rows per wave. fp16 in; fp16/fp32 out.
template <int C, bool BIAS, bool RELU, bool HOUT>
__global__ __launch_bounds__(256) void k_agg_v(const int* __restrict__ row_ptr,
                                               const int2* __restrict__ csr,
                                               const float* __restrict__ dis,
                                               const _Float16* __restrict__ in,
                                               void* __restrict__ out_,
                                               const float* __restrict__ bias, int N) {
    constexpr int LPR = C / 8;     // lanes per row
    constexpr int RPW = 64 / LPR;  // rows per wave
    const int wave = (int)(((long long)blockIdx.x * blockDim.x + threadIdx.x) >> 6);
    const int lane = threadIdx.x & 63;
    const int d = wave * RPW + lane / LPR;
    if (d >= N) return;
    const int c = (lane % LPR) * 8;
    const _Float16* __restrict__ inc = in + c;

    float acc[8];
    {
        half8 v = *(const half8*)(inc + (size_t)d * C);
        float dd = dis[d], ws = dd * dd;
#pragma unroll
        for (int k = 0; k < 8; ++k) acc[k] = ws * (float)v[k];
    }

    int j = row_ptr[d];
    const int hi = row_ptr[d + 1];
    // unroll 8: keep 8 x 16B gathers in flight per lane (probe: latency vs BW floor)
    for (; j + 7 < hi; j += 8) {
        int2 e[8];
#pragma unroll
        for (int u = 0; u < 8; ++u) e[u] = csr[j + u];
        half8 v[8];
#pragma unroll
        for (int u = 0; u < 8; ++u) v[u] = *(const half8*)(inc + (size_t)e[u].x * C);
#pragma unroll
        for (int u = 0; u < 8; ++u) {
            float w = __int_as_float(e[u].y);
#pragma unroll
            for (int k = 0; k < 8; ++k) acc[k] += w * (float)v[u][k];
        }
    }
    for (; j + 3 < hi; j += 4) {
        int2 e0 = csr[j + 0];
        int2 e1 = csr[j + 1];
        int2 e2 = csr[j + 2];
        int2 e3 = csr[j + 3];
        half8 v0 = *(const half8*)(inc + (size_t)e0.x * C);
        half8 v1 = *(const half8*)(inc + (size_t)e1.x * C);
        half8 v2 = *(const half8*)(inc + (size_t)e2.x * C);
        half8 v3 = *(const half8*)(inc + (size_t)e3.x * C);
        float w0 = __int_as_float(e0.y), w1 = __int_as_float(e1.y);
        float w2 = __int_as_float(e2.y), w3 = __int_as_float(e3.y);
#pragma unroll
        for (int k = 0; k < 8; ++k)
            acc[k] += w0 * (float)v0[k] + w1 * (float)v1[k] + w2 * (float)v2[k] + w3 * (float)v3[k];
    }
    for (; j < hi; ++j) {
        int2 e0 = csr[j];
        half8 v0 = *(const half8*)(inc + (size_t)e0.x * C);
        float w0 = __int_as_float(e0.y);
#pragma unroll
        for (int k = 0; k < 8; ++k) acc[k] += w0 * (float)v0[k];
    }

    if (BIAS) {
        float4 b0 = *(const float4*)(bias + c);
        float4 b1 = *(const float4*)(bias + c + 4);
        acc[0] += b0.x; acc[1] += b0.y; acc[2] += b0.z; acc[3] += b0.w;
        acc[4] += b1.x; acc[5] += b1.y; acc[6] += b1.z; acc[7] += b1.w;
    }
    if (RELU) {
#pragma unroll
        for (int k = 0; k < 8; ++k) acc[k] = fmaxf(acc[k], 0.f);
    }
    if constexpr (HOUT) {
        half8 h;
#pragma unroll
        for (int k = 0; k < 8; ++k) h[k] = (_Float16)acc[k];
        *(half8*)((_Float16*)out_ + (size_t)d * C + c) = h;
    } else {
        float* o = (float*)out_ + (size_t)d * C + c;
        *(float4*)o = make_float4(acc[0], acc[1], acc[2], acc[3]);
        *(float4*)(o + 4) = make_float4(acc[4], acc[5], acc[6], acc[7]);
    }
}

// ---------------- fp16 MFMA GEMM: C[M,CN] = A[M,K] @ W[K,CN] (+bias,+relu), fp16 out ----
template <int K, int CN, bool BIAS, bool RELU>
__global__ __launch_bounds__(256) void k_gemm_mfma(const _Float16* __restrict__ A,
                                                   const char* __restrict__ wt,
                                                   const float* __restrict__ bias,
                                                   _Float16* __restrict__ C, int M) {
    constexpr int T = K / 32;
    constexpr int NT = CN / 16;
    __shared__ __align__(16) char wlds[CN * K * 2];
    const int tid = threadIdx.x;
    for (int i = tid; i < CN * K / 8; i += 256)
        ((float4*)wlds)[i] = ((const float4*)wt)[i];
    __syncthreads();

    const int l = tid & 63;
    const int w = tid >> 6;
    const int r0 = blockIdx.x * 128 + w * 32;
    const int lm = l & 15;
    const int lg = l >> 4;
    const int sw = (l & 7) << 4;

    half8 af[2][T];
#pragma unroll
    for (int s = 0; s < 2; ++s) {
        int row = r0 + s * 16 + lm;
        row = row < M ? row : M - 1;
        const _Float16* ap = A + (size_t)row * K + lg * 8;
#pragma unroll
        for (int t = 0; t < T; ++t) af[s][t] = *(const half8*)(ap + t * 32);
    }

    f32x4 acc[2][NT] = {};
#pragma unroll
    for (int j = 0; j < NT; ++j) {
        const int n = j * 16 + lm;
        const char* bp = wlds + n * (2 * K);
        half8 bf[T];
#pragma unroll
        for (int t = 0; t < T; ++t)
            bf[t] = *(const half8*)(bp + ((t * 64 + lg * 16) ^ sw));
#pragma unroll
        for (int s = 0; s < 2; ++s)
#pragma unroll
            for (int t = 0; t < T; ++t)
                acc[s][j] = __builtin_amdgcn_mfma_f32_16x16x32_f16(bf[t], af[s][t], acc[s][j], 0, 0, 0);
    }

#pragma unroll
    for (int s = 0; s < 2; ++s) {
        const int m = r0 + s * 16 + lm;
        if (m >= M) continue;
#pragma unroll
        for (int j = 0; j < NT; ++j) {
            const int n0 = j * 16 + lg * 4;
            f32x4 v = acc[s][j];
            if (BIAS) {
                float4 b = *(const float4*)(bias + n0);
                v[0] += b.x; v[1] += b.y; v[2] += b.z; v[3] += b.w;
            }
            if (RELU) {
                v[0] = fmaxf(v[0], 0.f); v[1] = fmaxf(v[1], 0.f);
                v[2] = fmaxf(v[2], 0.f); v[3] = fmaxf(v[3], 0.f);
            }
            union { float2 f; __half2 h[2]; } u;
            u.h[0] = __floats2half2_rn(v[0], v[1]);
            u.h[1] = __floats2half2_rn(v[2], v[3]);
            *(float2*)(C + (size_t)m * CN + n0) = u.f;
        }
    }
}

extern "C" void kernel_launch(void* const* d_in, const int* in_sizes, int n_in,
                              void* d_out, int out_size, void* d_ws, size_t ws_size,
                              hipStream_t stream) {
    const float* x  = (const float*)d_in[0];
    const int* ei   = (const int*)d_in[1];   // int32 (JAX x64 disabled)
    const float* W1 = (const float*)d_in[2];
    const float* b1 = (const float*)d_in[3];
    const float* W2 = (const float*)d_in[4];
    const float* b2 = (const float*)d_in[5];
    const float* W3 = (const float*)d_in[6];
    const float* b3 = (const float*)d_in[7];
    float* out = (float*)d_out;

    const int N = in_sizes[0] / 128;  // 100000
    const int E = in_sizes[1] / 2;    // 1600000
    const int* dst = ei + E;
    const int nbk = cdiv(N, 1 << NBSH);  // 391 buckets

    // workspace layout (256B-aligned); aliased fp16 buffers:
    //   t2 := a1, h2 := h1, t3 := xh  (lifetimes disjoint)
    char* base = (char*)d_ws;
    size_t off = 0;
    auto take = [&](size_t bytes) {
        char* r = base + off;
        off += (bytes + 255) & ~(size_t)255;
        return r;
    };
    float* dis    = (float*)take((size_t)N * 4);
    int* row_ptr  = (int*)take((size_t)(N + 1) * 4);
    int* bcnt     = (int*)take((size_t)nbk * 4);
    int* bbase    = (int*)take((size_t)nbk * 4);
    int* ovf_cnt  = (int*)take(256);
    int2* csr     = (int2*)take((size_t)E * 8);
    char* binmem  = take((size_t)nbk * BCAP * 8);  // ebuf; fallback scratch aliases here
    int2* ovf     = (int2*)take((size_t)E * 8);
    _Float16* xh  = (_Float16*)take((size_t)N * 128 * 2);
    _Float16* a1  = (_Float16*)take((size_t)N * 128 * 2);
    _Float16* h1  = (_Float16*)take((size_t)N * 256 * 2);
    char* wt1     = take(256 * 128 * 2);
    char* wt2     = take(128 * 256 * 2);
    char* wt3     = take(64 * 128 * 2);
    _Float16* t2 = a1;   // a1 dead after gemm1
    _Float16* h2 = h1;   // h1 dead after gemm2
    _Float16* t3 = xh;   // xh dead after agg1

    const bool BUCKET = (off <= ws_size) && (nbk <= 1024);

    if (BUCKET) {
        int2* ebuf = (int2*)binmem;
        k_zero_bin<<<cdiv(nbk + 1, 256), 256, 0, stream>>>(bcnt, ovf_cnt, nbk);
        k_bin<<<cdiv(E, BCHUNK), 256, 0, stream>>>(ei, E, nbk, bcnt, ebuf, ovf, ovf_cnt);
        k_bscan<<<1, 1024, 0, stream>>>(bcnt, bbase, row_ptr, nbk, N);
        k_passB1<<<nbk, 256, 0, stream>>>(bcnt, bbase, ebuf, ovf, ovf_cnt, row_ptr, dis, N);
        k_passB2<<<nbk, 256, 0, stream>>>(bcnt, ebuf, ovf, ovf_cnt, row_ptr, dis, csr, N);
    } else {
        size_t o2 = 0;
        auto take2 = [&](size_t bytes) {
            char* r = binmem + o2;
            o2 += (bytes + 255) & ~(size_t)255;
            return r;
        };
        int* deg  = (int*)take2((size_t)N * 4);
        int* tmp  = (int*)take2((size_t)N * 4);
        int* bsum = (int*)take2((size_t)1024 * 4);
        int* cur  = (int*)take2((size_t)N * 4);
        const int nb = cdiv(N, 1024);
        k_zero_i<<<cdiv(N, 256), 256, 0, stream>>>(deg, N);
        k_count<<<cdiv(E, 256), 256, 0, stream>>>(dst, deg, E);
        k_scan1<<<nb, 1024, 0, stream>>>(deg, tmp, bsum, N);
        k_scan2<<<1, 1024, 0, stream>>>(bsum, nb);
        k_scan3<<<cdiv(N + 1, 1024), 1024, 0, stream>>>(deg, tmp, bsum, row_ptr, dis, cur, N, nb);
        k_scatter<<<cdiv(E, 256), 256, 0, stream>>>(ei, dis, cur, csr, E);
    }

    // ---- prep: x -> fp16; weights -> swizzled fp16 W^T ----
    k_cvt_h<<<cdiv((long long)N * 32, 256), 256, 0, stream>>>(x, (__half*)xh, (long long)N * 32);
    k_prep_wt<128, 256><<<cdiv(256 * 16, 256), 256, 0, stream>>>(W1, wt1);
    k_prep_wt<256, 128><<<cdiv(128 * 32, 256), 256, 0, stream>>>(W2, wt2);
    k_prep_wt<128, 64><<<cdiv(64 * 16, 256), 256, 0, stream>>>(W3, wt3);

    // agg grids: rows-per-wave depends on C
    const int gA128 = cdiv((long long)cdiv(N, 4) * 64, 256);  // C=128: 4 rows/wave
    const int gA64  = cdiv((long long)cdiv(N, 8) * 64, 256);  // C=64:  8 rows/wave
    const int gG = cdiv(N, 128);                              // gemm: 128 rows/block

    // ---- layer 1: a1 = agg(xh); h1 = relu(a1@W1 + b1) ----
    k_agg_v<128, false, false, true><<<gA128, 256, 0, stream>>>(row_ptr, csr, dis, xh, a1, nullptr, N);
    k_gemm_mfma<128, 256, true, true><<<gG, 256, 0, stream>>>(a1, wt1, b1, h1, N);

    // ---- layer 2: t2 = h1@W2; h2 = relu(agg(t2) + b2) ----
    k_gemm_mfma<256, 128, false, false><<<gG, 256, 0, stream>>>(h1, wt2, nullptr, t2, N);
    k_agg_v<128, true, true, true><<<gA128, 256, 0, stream>>>(row_ptr, csr, dis, t2, h2, b2, N);

    // ---- layer 3: t3 = h2@W3; out = agg(t3) + b3 ----
    k_gemm_mfma<128, 64, false, false><<<gG, 256, 0, stream>>>(h2, wt3, nullptr, t3, N);
    k_agg_v<64, true, false, false><<<gA64, 256, 0, stream>>>(row_ptr, csr, dis, t3, out, b3, N);
}

// Round 13
// 318.000 us; speedup vs baseline: 1.0260x; 1.0260x over previous
//
#include <hip/hip_runtime.h>
#include <hip/hip_fp16.h>

static inline int cdiv(long long a, long long b) { return (int)((a + b - 1) / b); }

typedef _Float16 half8 __attribute__((ext_vector_type(8)));
typedef float f32x4 __attribute__((ext_vector_type(4)));

#define NBSH 8            // 256 dsts per bucket
#define BCAP 6144         // bucket capacity in ebuf (avg 4096 for this graph; +50%)
#define BCHUNK 8192       // edges per k_bin block

// ---------------- binned CSR build (no global per-dst atomics) ----------------
__global__ void k_zero_bin(int* bcnt, int* ovf_cnt, int nbk) {
    int t = blockIdx.x * blockDim.x + threadIdx.x;
    if (t < nbk) bcnt[t] = 0;
    if (t == 0) *ovf_cnt = 0;
}

__global__ __launch_bounds__(256) void k_bin(const int* __restrict__ ei, int E, int nbk,
                                             int* __restrict__ bcnt,
                                             int2* __restrict__ ebuf,
                                             int2* __restrict__ ovf, int* __restrict__ ovf_cnt) {
    __shared__ int hist[1024];
    __shared__ int base[1024];
    const int tid = threadIdx.x;
    const int e0 = blockIdx.x * BCHUNK;
    if (e0 >= E) return;
    const int n = min(BCHUNK, E - e0);
    const int* __restrict__ srcs = ei + e0;
    const int* __restrict__ dsts = ei + E + e0;

    for (int i = tid; i < nbk; i += 256) hist[i] = 0;
    __syncthreads();
    for (int i = tid; i < n; i += 256) atomicAdd(&hist[dsts[i] >> NBSH], 1);
    __syncthreads();
    for (int b = tid; b < nbk; b += 256) {
        int h = hist[b];
        base[b] = h ? atomicAdd(&bcnt[b], h) : 0;
        hist[b] = 0;  // reuse as local offset
    }
    __syncthreads();
    for (int i = tid; i < n; i += 256) {
        int d = dsts[i];
        int s = srcs[i];
        int b = d >> NBSH;
        int pos = base[b] + atomicAdd(&hist[b], 1);
        if (pos < BCAP) {
            ebuf[(size_t)b * BCAP + pos] = make_int2(s, d);
        } else {
            int op = atomicAdd(ovf_cnt, 1);
            ovf[op] = make_int2(s, d);
        }
    }
}

__global__ __launch_bounds__(1024) void k_bscan(const int* __restrict__ bcnt,
                                                int* __restrict__ bbase,
                                                int* __restrict__ row_ptr, int nbk, int N) {
    __shared__ int s[1024];
    const int t = threadIdx.x;
    int v = (t < nbk) ? bcnt[t] : 0;
    s[t] = v;
    __syncthreads();
    for (int off = 1; off < 1024; off <<= 1) {
        int u = (t >= off) ? s[t - off] : 0;
        __syncthreads();
        s[t] += u;
        __syncthreads();
    }
    if (t < nbk) bbase[t] = s[t] - v;
    if (t == nbk - 1) row_ptr[N] = s[t];
}

__global__ __launch_bounds__(256) void k_passB1(const int* __restrict__ bcnt,
                                                const int* __restrict__ bbase,
                                                const int2* __restrict__ ebuf,
                                                const int2* __restrict__ ovf,
                                                const int* __restrict__ ovf_cnt,
                                                int* __restrict__ row_ptr,
                                                float* __restrict__ dis, int N) {
    __shared__ int ldeg[256];
    __shared__ int sc[256];
    const int tid = threadIdx.x;
    const int b = blockIdx.x;
    const int d0 = b << NBSH;
    const int dn = min(1 << NBSH, N - d0);
    ldeg[tid] = 0;
    __syncthreads();
    const int sz = min(bcnt[b], BCAP);
    const int2* __restrict__ reg = ebuf + (size_t)b * BCAP;
    for (int i = tid; i < sz; i += 256) atomicAdd(&ldeg[reg[i].y - d0], 1);
    const int oc = *ovf_cnt;
    for (int i = tid; i < oc; i += 256) {
        int d = ovf[i].y;
        if ((d >> NBSH) == b) atomicAdd(&ldeg[d - d0], 1);
    }
    __syncthreads();
    sc[tid] = ldeg[tid];
    __syncthreads();
    for (int off = 1; off < 256; off <<= 1) {
        int u = (tid >= off) ? sc[tid - off] : 0;
        __syncthreads();
        sc[tid] += u;
        __syncthreads();
    }
    if (tid < dn) {
        row_ptr[d0 + tid] = bbase[b] + sc[tid] - ldeg[tid];
        dis[d0 + tid] = rsqrtf((float)(ldeg[tid] + 1));  // +1 self-loop
    }
}

__global__ __launch_bounds__(256) void k_passB2(const int* __restrict__ bcnt,
                                                const int2* __restrict__ ebuf,
                                                const int2* __restrict__ ovf,
                                                const int* __restrict__ ovf_cnt,
                                                const int* __restrict__ row_ptr,
                                                const float* __restrict__ dis,
                                                int2* __restrict__ csr, int N) {
    __shared__ int lcur[256];
    const int tid = threadIdx.x;
    const int b = blockIdx.x;
    const int d0 = b << NBSH;
    const int dn = min(1 << NBSH, N - d0);
    lcur[tid] = (tid < dn) ? row_ptr[d0 + tid] : 0;
    __syncthreads();
    const int sz = min(bcnt[b], BCAP);
    const int2* __restrict__ reg = ebuf + (size_t)b * BCAP;
    for (int i = tid; i < sz; i += 256) {
        int2 sd = reg[i];
        float w = dis[sd.x] * dis[sd.y];
        int pos = atomicAdd(&lcur[sd.y - d0], 1);
        csr[pos] = make_int2(sd.x, __float_as_int(w));
    }
    const int oc = *ovf_cnt;
    for (int i = tid; i < oc; i += 256) {
        int2 sd = ovf[i];
        if ((sd.y >> NBSH) != b) continue;
        float w = dis[sd.x] * dis[sd.y];
        int pos = atomicAdd(&lcur[sd.y - d0], 1);
        csr[pos] = make_int2(sd.x, __float_as_int(w));
    }
}

// ---------------- fallback CSR build (round-7 path, used only if ws too small) ----------------
__global__ void k_zero_i(int* p, int n) {
    int t = blockIdx.x * blockDim.x + threadIdx.x;
    if (t < n) p[t] = 0;
}

__global__ void k_count(const int* __restrict__ dst, int* __restrict__ deg, int E) {
    int t = blockIdx.x * blockDim.x + threadIdx.x;
    if (t < E) atomicAdd(&deg[dst[t]], 1);
}

__global__ __launch_bounds__(1024) void k_scan1(const int* __restrict__ deg,
                                                int* __restrict__ tmp,
                                                int* __restrict__ bsum, int n) {
    __shared__ int s[1024];
    const int t = threadIdx.x;
    const int i = blockIdx.x * 1024 + t;
    int v = (i < n) ? deg[i] : 0;
    s[t] = v;
    __syncthreads();
    for (int off = 1; off < 1024; off <<= 1) {
        int u = (t >= off) ? s[t - off] : 0;
        __syncthreads();
        s[t] += u;
        __syncthreads();
    }
    if (i < n) tmp[i] = s[t];
    if (t == 1023) bsum[blockIdx.x] = s[1023];
}

__global__ __launch_bounds__(1024) void k_scan2(int* __restrict__ bsum, int nb) {
    __shared__ int s[1024];
    const int t = threadIdx.x;
    s[t] = (t < nb) ? bsum[t] : 0;
    __syncthreads();
    for (int off = 1; off < 1024; off <<= 1) {
        int u = (t >= off) ? s[t - off] : 0;
        __syncthreads();
        s[t] += u;
        __syncthreads();
    }
    if (t < nb) bsum[t] = s[t];
}

__global__ __launch_bounds__(1024) void k_scan3(const int* __restrict__ deg,
                                                const int* __restrict__ tmp,
                                                const int* __restrict__ bsum,
                                                int* __restrict__ row_ptr,
                                                float* __restrict__ dis,
                                                int* __restrict__ cur, int n, int nb) {
    const int i = blockIdx.x * 1024 + threadIdx.x;
    if (i < n) {
        int off = (blockIdx.x == 0) ? 0 : bsum[blockIdx.x - 1];
        int dgi = deg[i];
        int r = tmp[i] - dgi + off;
        row_ptr[i] = r;
        dis[i] = rsqrtf((float)(dgi + 1));
        cur[i] = r;
    } else if (i == n) {
        row_ptr[n] = bsum[nb - 1];
    }
}

__global__ void k_scatter(const int* __restrict__ ei, const float* __restrict__ dis,
                          int* __restrict__ cur, int2* __restrict__ csr, int E) {
    int e = blockIdx.x * blockDim.x + threadIdx.x;
    if (e >= E) return;
    int s = ei[e];
    int d = ei[e + E];
    float w = dis[s] * dis[d];
    int pos = atomicAdd(&cur[d], 1);
    csr[pos] = make_int2(s, __float_as_int(w));
}

// ---------------- fp32 -> fp16 convert ----------------
__global__ __launch_bounds__(256) void k_cvt_h(const float* __restrict__ in,
                                               __half* __restrict__ out, long long n4) {
    long long t = (long long)blockIdx.x * blockDim.x + threadIdx.x;
    if (t >= n4) return;
    float4 v = *(const float4*)(in + t * 4);
    union { float2 f; __half2 h[2]; } u;
    u.h[0] = __floats2half2_rn(v.x, v.y);
    u.h[1] = __floats2half2_rn(v.z, v.w);
    *(float2*)(out + t * 4) = u.f;
}

// ---------------- weight prep: W fp32 [K][CN] -> swizzled fp16 W^T [CN][K] ----------------
template <int K, int CN>
__global__ void k_prep_wt(const float* __restrict__ W, char* __restrict__ wt) {
    constexpr int CH = K / 8;
    int id = blockIdx.x * blockDim.x + threadIdx.x;
    if (id >= CN * CH) return;
    int n = id / CH, c = id % CH;
    half8 h;
#pragma unroll
    for (int j = 0; j < 8; ++j) h[j] = (_Float16)W[(size_t)(c * 8 + j) * CN + n];
    *(half8*)(wt + (size_t)n * (2 * K) + ((c * 16) ^ ((n & 7) << 4))) = h;
}

// ---------------- vectorized fused aggregation (round-10 optimum: unroll 4) ----------------
// out[d][:] = (BIAS? b:0) + dis[d]^2*in[d][:] + sum_e w_e*in[src_e][:]; optional ReLU.
// C/8 lanes per row (16B half8 loads), 64/(C/8) rows per wave. fp16 in; fp16/fp32 out.
// unroll 4 chosen empirically: unroll 8 raised VGPR 32->44, dropped occupancy 68->44%,
// and regressed 62.5->65.3 us (round 12). Degree-sorted scheduling also regressed
// (round 11: destroyed write/self-read locality). This phase is at its random-gather
// bandwidth floor (~3.6 TB/s effective L2-miss traffic, FETCH ~195 MB structural).
template <int C, bool BIAS, bool RELU, bool HOUT>
__global__ __launch_bounds__(256) void k_agg_v(const int* __restrict__ row_ptr,
                                               const int2* __restrict__ csr,
                                               const float* __restrict__ dis,
                                               const _Float16* __restrict__ in,
                                               void* __restrict__ out_,
                                               const float* __restrict__ bias, int N) {
    constexpr int LPR = C / 8;     // lanes per row
    constexpr int RPW = 64 / LPR;  // rows per wave
    const int wave = (int)(((long long)blockIdx.x * blockDim.x + threadIdx.x) >> 6);
    const int lane = threadIdx.x & 63;
    const int d = wave * RPW + lane / LPR;
    if (d >= N) return;
    const int c = (lane % LPR) * 8;
    const _Float16* __restrict__ inc = in + c;

    float acc[8];
    {
        half8 v = *(const half8*)(inc + (size_t)d * C);
        float dd = dis[d], ws = dd * dd;
#pragma unroll
        for (int k = 0; k < 8; ++k) acc[k] = ws * (float)v[k];
    }

    int j = row_ptr[d];
    const int hi = row_ptr[d + 1];
    for (; j + 3 < hi; j += 4) {  // 4 x 16B gathers in flight per lane
        int2 e0 = csr[j + 0];
        int2 e1 = csr[j + 1];
        int2 e2 = csr[j + 2];
        int2 e3 = csr[j + 3];
        half8 v0 = *(const half8*)(inc + (size_t)e0.x * C);
        half8 v1 = *(const half8*)(inc + (size_t)e1.x * C);
        half8 v2 = *(const half8*)(inc + (size_t)e2.x * C);
        half8 v3 = *(const half8*)(inc + (size_t)e3.x * C);
        float w0 = __int_as_float(e0.y), w1 = __int_as_float(e1.y);
        float w2 = __int_as_float(e2.y), w3 = __int_as_float(e3.y);
#pragma unroll
        for (int k = 0; k < 8; ++k)
            acc[k] += w0 * (float)v0[k] + w1 * (float)v1[k] + w2 * (float)v2[k] + w3 * (float)v3[k];
    }
    for (; j < hi; ++j) {
        int2 e0 = csr[j];
        half8 v0 = *(const half8*)(inc + (size_t)e0.x * C);
        float w0 = __int_as_float(e0.y);
#pragma unroll
        for (int k = 0; k < 8; ++k) acc[k] += w0 * (float)v0[k];
    }

    if (BIAS) {
        float4 b0 = *(const float4*)(bias + c);
        float4 b1 = *(const float4*)(bias + c + 4);
        acc[0] += b0.x; acc[1] += b0.y; acc[2] += b0.z; acc[3] += b0.w;
        acc[4] += b1.x; acc[5] += b1.y; acc[6] += b1.z; acc[7] += b1.w;
    }
    if (RELU) {
#pragma unroll
        for (int k = 0; k < 8; ++k) acc[k] = fmaxf(acc[k], 0.f);
    }
    if constexpr (HOUT) {
        half8 h;
#pragma unroll
        for (int k = 0; k < 8; ++k) h[k] = (_Float16)acc[k];
        *(half8*)((_Float16*)out_ + (size_t)d * C + c) = h;
    } else {
        float* o = (float*)out_ + (size_t)d * C + c;
        *(float4*)o = make_float4(acc[0], acc[1], acc[2], acc[3]);
        *(float4*)(o + 4) = make_float4(acc[4], acc[5], acc[6], acc[7]);
    }
}

// ---------------- fp16 MFMA GEMM: C[M,CN] = A[M,K] @ W[K,CN] (+bias,+relu), fp16 out ----
template <int K, int CN, bool BIAS, bool RELU>
__global__ __launch_bounds__(256) void k_gemm_mfma(const _Float16* __restrict__ A,
                                                   const char* __restrict__ wt,
                                                   const float* __restrict__ bias,
                                                   _Float16* __restrict__ C, int M) {
    constexpr int T = K / 32;
    constexpr int NT = CN / 16;
    __shared__ __align__(16) char wlds[CN * K * 2];
    const int tid = threadIdx.x;
    for (int i = tid; i < CN * K / 8; i += 256)
        ((float4*)wlds)[i] = ((const float4*)wt)[i];
    __syncthreads();

    const int l = tid & 63;
    const int w = tid >> 6;
    const int r0 = blockIdx.x * 128 + w * 32;
    const int lm = l & 15;
    const int lg = l >> 4;
    const int sw = (l & 7) << 4;

    half8 af[2][T];
#pragma unroll
    for (int s = 0; s < 2; ++s) {
        int row = r0 + s * 16 + lm;
        row = row < M ? row : M - 1;
        const _Float16* ap = A + (size_t)row * K + lg * 8;
#pragma unroll
        for (int t = 0; t < T; ++t) af[s][t] = *(const half8*)(ap + t * 32);
    }

    f32x4 acc[2][NT] = {};
#pragma unroll
    for (int j = 0; j < NT; ++j) {
        const int n = j * 16 + lm;
        const char* bp = wlds + n * (2 * K);
        half8 bf[T];
#pragma unroll
        for (int t = 0; t < T; ++t)
            bf[t] = *(const half8*)(bp + ((t * 64 + lg * 16) ^ sw));
#pragma unroll
        for (int s = 0; s < 2; ++s)
#pragma unroll
            for (int t = 0; t < T; ++t)
                acc[s][j] = __builtin_amdgcn_mfma_f32_16x16x32_f16(bf[t], af[s][t], acc[s][j], 0, 0, 0);
    }

#pragma unroll
    for (int s = 0; s < 2; ++s) {
        const int m = r0 + s * 16 + lm;
        if (m >= M) continue;
#pragma unroll
        for (int j = 0; j < NT; ++j) {
            const int n0 = j * 16 + lg * 4;
            f32x4 v = acc[s][j];
            if (BIAS) {
                float4 b = *(const float4*)(bias + n0);
                v[0] += b.x; v[1] += b.y; v[2] += b.z; v[3] += b.w;
            }
            if (RELU) {
                v[0] = fmaxf(v[0], 0.f); v[1] = fmaxf(v[1], 0.f);
                v[2] = fmaxf(v[2], 0.f); v[3] = fmaxf(v[3], 0.f);
            }
            union { float2 f; __half2 h[2]; } u;
            u.h[0] = __floats2half2_rn(v[0], v[1]);
            u.h[1] = __floats2half2_rn(v[2], v[3]);
            *(float2*)(C + (size_t)m * CN + n0) = u.f;
        }
    }
}

extern "C" void kernel_launch(void* const* d_in, const int* in_sizes, int n_in,
                              void* d_out, int out_size, void* d_ws, size_t ws_size,
                              hipStream_t stream) {
    const float* x  = (const float*)d_in[0];
    const int* ei   = (const int*)d_in[1];   // int32 (JAX x64 disabled)
    const float* W1 = (const float*)d_in[2];
    const float* b1 = (const float*)d_in[3];
    const float* W2 = (const float*)d_in[4];
    const float* b2 = (const float*)d_in[5];
    const float* W3 = (const float*)d_in[6];
    const float* b3 = (const float*)d_in[7];
    float* out = (float*)d_out;

    const int N = in_sizes[0] / 128;  // 100000
    const int E = in_sizes[1] / 2;    // 1600000
    const int* dst = ei + E;
    const int nbk = cdiv(N, 1 << NBSH);  // 391 buckets

    // workspace layout (256B-aligned); aliased fp16 buffers:
    //   t2 := a1, h2 := h1, t3 := xh  (lifetimes disjoint)
    char* base = (char*)d_ws;
    size_t off = 0;
    auto take = [&](size_t bytes) {
        char* r = base + off;
        off += (bytes + 255) & ~(size_t)255;
        return r;
    };
    float* dis    = (float*)take((size_t)N * 4);
    int* row_ptr  = (int*)take((size_t)(N + 1) * 4);
    int* bcnt     = (int*)take((size_t)nbk * 4);
    int* bbase    = (int*)take((size_t)nbk * 4);
    int* ovf_cnt  = (int*)take(256);
    int2* csr     = (int2*)take((size_t)E * 8);
    char* binmem  = take((size_t)nbk * BCAP * 8);  // ebuf; fallback scratch aliases here
    int2* ovf     = (int2*)take((size_t)E * 8);
    _Float16* xh  = (_Float16*)take((size_t)N * 128 * 2);
    _Float16* a1  = (_Float16*)take((size_t)N * 128 * 2);
    _Float16* h1  = (_Float16*)take((size_t)N * 256 * 2);
    char* wt1     = take(256 * 128 * 2);
    char* wt2     = take(128 * 256 * 2);
    char* wt3     = take(64 * 128 * 2);
    _Float16* t2 = a1;   // a1 dead after gemm1
    _Float16* h2 = h1;   // h1 dead after gemm2
    _Float16* t3 = xh;   // xh dead after agg1

    const bool BUCKET = (off <= ws_size) && (nbk <= 1024);

    if (BUCKET) {
        int2* ebuf = (int2*)binmem;
        k_zero_bin<<<cdiv(nbk + 1, 256), 256, 0, stream>>>(bcnt, ovf_cnt, nbk);
        k_bin<<<cdiv(E, BCHUNK), 256, 0, stream>>>(ei, E, nbk, bcnt, ebuf, ovf, ovf_cnt);
        k_bscan<<<1, 1024, 0, stream>>>(bcnt, bbase, row_ptr, nbk, N);
        k_passB1<<<nbk, 256, 0, stream>>>(bcnt, bbase, ebuf, ovf, ovf_cnt, row_ptr, dis, N);
        k_passB2<<<nbk, 256, 0, stream>>>(bcnt, ebuf, ovf, ovf_cnt, row_ptr, dis, csr, N);
    } else {
        size_t o2 = 0;
        auto take2 = [&](size_t bytes) {
            char* r = binmem + o2;
            o2 += (bytes + 255) & ~(size_t)255;
            return r;
        };
        int* deg  = (int*)take2((size_t)N * 4);
        int* tmp  = (int*)take2((size_t)N * 4);
        int* bsum = (int*)take2((size_t)1024 * 4);
        int* cur  = (int*)take2((size_t)N * 4);
        const int nb = cdiv(N, 1024);
        k_zero_i<<<cdiv(N, 256), 256, 0, stream>>>(deg, N);
        k_count<<<cdiv(E, 256), 256, 0, stream>>>(dst, deg, E);
        k_scan1<<<nb, 1024, 0, stream>>>(deg, tmp, bsum, N);
        k_scan2<<<1, 1024, 0, stream>>>(bsum, nb);
        k_scan3<<<cdiv(N + 1, 1024), 1024, 0, stream>>>(deg, tmp, bsum, row_ptr, dis, cur, N, nb);
        k_scatter<<<cdiv(E, 256), 256, 0, stream>>>(ei, dis, cur, csr, E);
    }

    // ---- prep: x -> fp16; weights -> swizzled fp16 W^T ----
    k_cvt_h<<<cdiv((long long)N * 32, 256), 256, 0, stream>>>(x, (__half*)xh, (long long)N * 32);
    k_prep_wt<128, 256><<<cdiv(256 * 16, 256), 256, 0, stream>>>(W1, wt1);
    k_prep_wt<256, 128><<<cdiv(128 * 32, 256), 256, 0, stream>>>(W2, wt2);
    k_prep_wt<128, 64><<<cdiv(64 * 16, 256), 256, 0, stream>>>(W3, wt3);

    // agg grids: rows-per-wave depends on C
    const int gA128 = cdiv((long long)cdiv(N, 4) * 64, 256);  // C=128: 4 rows/wave
    const int gA64  = cdiv((long long)cdiv(N, 8) * 64, 256);  // C=64:  8 rows/wave
    const int gG = cdiv(N, 128);                              // gemm: 128 rows/block

    // ---- layer 1: a1 = agg(xh); h1 = relu(a1@W1 + b1) ----
    k_agg_v<128, false, false, true><<<gA128, 256, 0, stream>>>(row_ptr, csr, dis, xh, a1, nullptr, N);
    k_gemm_mfma<128, 256, true, true><<<gG, 256, 0, stream>>>(a1, wt1, b1, h1, N);

    // ---- layer 2: t2 = h1@W2; h2 = relu(agg(t2) + b2) ----
    k_gemm_mfma<256, 128, false, false><<<gG, 256, 0, stream>>>(h1, wt2, nullptr, t2, N);
    k_agg_v<128, true, true, true><<<gA128, 256, 0, stream>>>(row_ptr, csr, dis, t2, h2, b2, N);

    // ---- layer 3: t3 = h2@W3; out = agg(t3) + b3 ----
    k_gemm_mfma<128, 64, false, false><<<gG, 256, 0, stream>>>(h2, wt3, nullptr, t3, N);
    k_agg_v<64, true, false, false><<<gA64, 256, 0, stream>>>(row_ptr, csr, dis, t3, out, b3, N);
}